// Round 2
// baseline (462.515 us; speedup 1.0000x reference)
//
#include <hip/hip_runtime.h>
#include <hip/hip_bf16.h>

typedef __attribute__((ext_vector_type(8))) short bf16x8;
typedef __attribute__((ext_vector_type(4))) short short4v;
typedef __attribute__((ext_vector_type(4))) float f32x4;

#define TAU_INV 2.0f

__device__ __forceinline__ short f2bf(float f) {
  unsigned u = __float_as_uint(f);
  u += 0x7fffu + ((u >> 16) & 1u);
  return (short)(u >> 16);
}
__device__ __forceinline__ float bf2f(short s) {
  return __uint_as_float(((unsigned)(unsigned short)s) << 16);
}

// ---------------- weight prep: transpose to [c][k] + bf16 ----------------
__global__ __launch_bounds__(256) void prep_weights(
    const float* __restrict__ w_state, const float* __restrict__ w_inj,
    const float* __restrict__ w_ga, const float* __restrict__ w_gb,
    const float* __restrict__ w_s1, const float* __restrict__ w_out,
    short* __restrict__ t_state, short* __restrict__ t_inj,
    short* __restrict__ t_ga, short* __restrict__ t_gb,
    short* __restrict__ t_s1, short* __restrict__ t_out)
{
  int idx = blockIdx.x * 256 + threadIdx.x;
  const float* src; short* dst; int C, K;
  if (idx < 294912)                  { src = w_state; dst = t_state; C = 768; K = 384; }
  else if ((idx -= 294912) < 294912) { src = w_inj;   dst = t_inj;   C = 768; K = 384; }
  else if ((idx -= 294912) < 147456) { src = w_ga;    dst = t_ga;    C = 384; K = 384; }
  else if ((idx -= 147456) < 147456) { src = w_gb;    dst = t_gb;    C = 384; K = 384; }
  else if ((idx -= 147456) < 147456) { src = w_s1;    dst = t_s1;    C = 384; K = 384; }
  else           { idx -= 147456;      src = w_out;   dst = t_out;   C = 384; K = 768; }
  int c = idx / K, k = idx - c * K;
  dst[c * K + k] = f2bf(src[k * C + c]);
}

// ---------------- GEMM over x: C = x @ W, epilogues ----------------
// EP 0: split 768 cols -> u/v grids (bf16, transposed store)
// EP 1: sigmoid(acc + bias) -> grid bf16
// EP 2: silu(acc + bias) -> natural [m][c] bf16
template<int EP>
__global__ __launch_bounds__(256) void gemm_x(
    const float* __restrict__ X, const short* __restrict__ Wt,
    const float* __restrict__ bias,
    short* __restrict__ out0, short* __restrict__ out1)
{
  __shared__ short As[128 * 72];
  __shared__ short Bs[128 * 72];
  const int tid = threadIdx.x;
  const int lane = tid & 63;
  const int wv = tid >> 6;
  const int wr = wv >> 1, wc = wv & 1;
  const int m0 = blockIdx.x * 128, c0 = blockIdx.y * 128;
  const int l15 = lane & 15, l4 = lane >> 4;
  f32x4 acc[4][4] = {};
  for (int k0 = 0; k0 < 384; k0 += 64) {
    __syncthreads();
#pragma unroll
    for (int i = 0; i < 8; ++i) {
      int q = tid + i * 256;
      int m = q >> 4, kq = (q & 15) * 4;
      const float4 xv = *(const float4*)(X + (m0 + m) * 384 + k0 + kq);
      short4v s;
      s[0] = f2bf(xv.x); s[1] = f2bf(xv.y); s[2] = f2bf(xv.z); s[3] = f2bf(xv.w);
      *(short4v*)(As + m * 72 + kq) = s;
    }
#pragma unroll
    for (int i = 0; i < 4; ++i) {
      int h = tid + i * 256;
      int c = h >> 3, kc = (h & 7) * 8;
      bf16x8 wvv = *(const bf16x8*)(Wt + (c0 + c) * 384 + k0 + kc);
      *(bf16x8*)(Bs + c * 72 + kc) = wvv;
    }
    __syncthreads();
#pragma unroll
    for (int kk = 0; kk < 2; ++kk) {
      bf16x8 af[4], bfv[4];
#pragma unroll
      for (int f = 0; f < 4; ++f) {
        af[f]  = *(const bf16x8*)(As + (wr * 64 + f * 16 + l15) * 72 + kk * 32 + l4 * 8);
        bfv[f] = *(const bf16x8*)(Bs + (wc * 64 + f * 16 + l15) * 72 + kk * 32 + l4 * 8);
      }
#pragma unroll
      for (int i = 0; i < 4; ++i)
#pragma unroll
        for (int j = 0; j < 4; ++j)
          acc[i][j] = __builtin_amdgcn_mfma_f32_16x16x32_bf16(af[i], bfv[j], acc[i][j], 0, 0, 0);
    }
  }
#pragma unroll
  for (int i = 0; i < 4; ++i) {
#pragma unroll
    for (int j = 0; j < 4; ++j) {
      const int c = c0 + wc * 64 + j * 16 + l15;
      const int mb = m0 + wr * 64 + i * 16 + l4 * 4;
      f32x4 v = acc[i][j];
      if (EP == 0) {
        short4v s;
        s[0] = f2bf(v[0]); s[1] = f2bf(v[1]); s[2] = f2bf(v[2]); s[3] = f2bf(v[3]);
        int b = mb >> 12, n = mb & 4095;
        short* base = (c < 384) ? out0 : out1;
        int plane = (c >= 384) ? (c - 384) : c;   // FIX: 384 is not a pow2 mask
        *(short4v*)(base + (b * 384 + plane) * 4096 + n) = s;
      } else if (EP == 1) {
        float bb = bias[c];
        short4v s;
#pragma unroll
        for (int r = 0; r < 4; ++r) {
          float t = v[r] + bb;
          t = 1.f / (1.f + __expf(-t));
          s[r] = f2bf(t);
        }
        int b = mb >> 12, n = mb & 4095;
        *(short4v*)(out0 + (b * 384 + c) * 4096 + n) = s;
      } else {
        float bb = bias[c];
#pragma unroll
        for (int r = 0; r < 4; ++r) {
          float t = v[r] + bb;
          float sg = 1.f / (1.f + __expf(-t));
          out0[(mb + r) * 384 + c] = f2bf(t * sg);
        }
      }
    }
  }
}

// ---------------- psi: s1 @ W_stream2 + b2, wave-per-row ----------------
__global__ __launch_bounds__(256) void psi_kernel(
    const short* __restrict__ S1, const float* __restrict__ W2,
    const float* __restrict__ b2, float* __restrict__ psi)
{
  const int lane = threadIdx.x & 63;
  const int wv = threadIdx.x >> 6;
  const int m = blockIdx.x * 4 + wv;
  float a0 = 0.f, a1 = 0.f, a2 = 0.f, a3 = 0.f;
#pragma unroll
  for (int t = 0; t < 6; ++t) {
    int k = lane + t * 64;
    float sv = bf2f(S1[m * 384 + k]);
    float4 wr = *(const float4*)(W2 + k * 4);
    a0 += sv * wr.x; a1 += sv * wr.y; a2 += sv * wr.z; a3 += sv * wr.w;
  }
  for (int off = 32; off > 0; off >>= 1) {
    a0 += __shfl_down(a0, off, 64);
    a1 += __shfl_down(a1, off, 64);
    a2 += __shfl_down(a2, off, 64);
    a3 += __shfl_down(a3, off, 64);
  }
  if (lane == 0) {
    int bb = m >> 12, n = m & 4095;
    psi[(bb * 4 + 0) * 4096 + n] = a0 + b2[0];
    psi[(bb * 4 + 1) * 4096 + n] = a1 + b2[1];
    psi[(bb * 4 + 2) * 4096 + n] = a2 + b2[2];
    psi[(bb * 4 + 3) * 4096 + n] = a3 + b2[3];
  }
}

// ---------------- routing: central diffs + softmax(5) ----------------
__global__ __launch_bounds__(256) void routing_kernel(
    const float* __restrict__ psi, const float* __restrict__ sb,
    float* __restrict__ R)
{
  const int idx = blockIdx.x * 256 + threadIdx.x;   // < 131072
  const int n = idx & 4095, bg = idx >> 12;
  const int i = n >> 6, j = n & 63;
  const float* p = psi + bg * 4096;
  float up = (i > 0)  ? p[n - 64] : 0.f;   // psi[i-1]
  float dn = (i < 63) ? p[n + 64] : 0.f;   // psi[i+1]
  float lf = (j > 0)  ? p[n - 1]  : 0.f;
  float rt = (j < 63) ? p[n + 1]  : 0.f;
  float vx = 0.5f * (dn - up);
  float vy = -0.5f * (rt - lf);
  float l0 = sb[bg & 3];
  float l1 = -vx * TAU_INV, l2 = vx * TAU_INV, l3 = -vy * TAU_INV, l4v = vy * TAU_INV;
  float mx = fmaxf(fmaxf(fmaxf(l0, l1), fmaxf(l2, l3)), l4v);
  float e0 = __expf(l0 - mx), e1 = __expf(l1 - mx), e2 = __expf(l2 - mx);
  float e3 = __expf(l3 - mx), e4 = __expf(l4v - mx);
  float inv = 1.f / (e0 + e1 + e2 + e3 + e4);
  const int NP = 8 * 4 * 4096;
  R[0 * NP + idx] = e0 * inv;
  R[1 * NP + idx] = e1 * inv;
  R[2 * NP + idx] = e2 * inv;
  R[3 * NP + idx] = e3 * inv;
  R[4 * NP + idx] = e4 * inv;
}

// ---------------- transport: 4 gated stencil steps, plane-resident in LDS ----------------
__global__ __launch_bounds__(512, 2) void transport_kernel(
    short* __restrict__ Ug, short* __restrict__ Vg,
    const short* __restrict__ Ga, const short* __restrict__ Gb,
    const short* __restrict__ Xu, const short* __restrict__ Xv,
    const float* __restrict__ R, const int* __restrict__ ksp)
{
  __shared__ float su[4096];
  __shared__ float sv[4096];
  const int tid = threadIdx.x;
  const int bd = blockIdx.x;            // b*384 + d
  const int b = bd / 384;
  const int d = bd - b * 384;
  const int g = d / 96;
  const int pbase = bd * 4096;
  const int rbase = (b * 4 + g) * 4096;
  const int NP = 8 * 4 * 4096;
  const int p0 = tid * 8;
  const int i = tid >> 3;
  const int j0 = (tid & 7) * 8;
  const int s = i & 7;                  // LDS word swizzle: w ^ ((w>>6)&7)

  float ga[8], gb[8], xu[8], xv[8], r0[8], r1[8], r2[8], r3[8], r4[8];
  {
    bf16x8 t;
    t = *(const bf16x8*)(Ga + pbase + p0);
#pragma unroll
    for (int c = 0; c < 8; ++c) ga[c] = bf2f(t[c]);
    t = *(const bf16x8*)(Gb + pbase + p0);
#pragma unroll
    for (int c = 0; c < 8; ++c) gb[c] = bf2f(t[c]);
    t = *(const bf16x8*)(Xu + pbase + p0);
#pragma unroll
    for (int c = 0; c < 8; ++c) xu[c] = bf2f(t[c]);
    t = *(const bf16x8*)(Xv + pbase + p0);
#pragma unroll
    for (int c = 0; c < 8; ++c) xv[c] = bf2f(t[c]);
  }
#pragma unroll
  for (int q = 0; q < 2; ++q) {
    float4 f0 = *(const float4*)(R + 0 * NP + rbase + p0 + q * 4);
    float4 f1 = *(const float4*)(R + 1 * NP + rbase + p0 + q * 4);
    float4 f2 = *(const float4*)(R + 2 * NP + rbase + p0 + q * 4);
    float4 f3 = *(const float4*)(R + 3 * NP + rbase + p0 + q * 4);
    float4 f4 = *(const float4*)(R + 4 * NP + rbase + p0 + q * 4);
    r0[q*4+0]=f0.x; r0[q*4+1]=f0.y; r0[q*4+2]=f0.z; r0[q*4+3]=f0.w;
    r1[q*4+0]=f1.x; r1[q*4+1]=f1.y; r1[q*4+2]=f1.z; r1[q*4+3]=f1.w;
    r2[q*4+0]=f2.x; r2[q*4+1]=f2.y; r2[q*4+2]=f2.z; r2[q*4+3]=f2.w;
    r3[q*4+0]=f3.x; r3[q*4+1]=f3.y; r3[q*4+2]=f3.z; r3[q*4+3]=f3.w;
    r4[q*4+0]=f4.x; r4[q*4+1]=f4.y; r4[q*4+2]=f4.z; r4[q*4+3]=f4.w;
  }
  {
    bf16x8 tu = *(const bf16x8*)(Ug + pbase + p0);
    bf16x8 tv = *(const bf16x8*)(Vg + pbase + p0);
#pragma unroll
    for (int c = 0; c < 8; ++c) { su[p0 + (c ^ s)] = bf2f(tu[c]); sv[p0 + (c ^ s)] = bf2f(tv[c]); }
  }
  __syncthreads();
  const int ks = ksp[0];
  const bool hasUp = (i > 0), hasDn = (i < 63);
  const int sU = (i - 1) & 7, sD = (i + 1) & 7;
  for (int step = 0; step < ks; ++step) {
    float cu[8], cv[8], nu[8], nv[8];
#pragma unroll
    for (int c = 0; c < 8; ++c) { cu[c] = su[p0 + (c ^ s)]; cv[c] = sv[p0 + (c ^ s)]; }
    float luu = (j0 > 0)  ? su[(p0 - 1) ^ s] : 0.f;
    float luv = (j0 > 0)  ? sv[(p0 - 1) ^ s] : 0.f;
    float ruu = (j0 < 56) ? su[(p0 + 8) ^ s] : 0.f;
    float ruv = (j0 < 56) ? sv[(p0 + 8) ^ s] : 0.f;
#pragma unroll
    for (int c = 0; c < 8; ++c) {
      float upU = hasUp ? su[(p0 - 64) + (c ^ sU)] : 0.f;
      float upV = hasUp ? sv[(p0 - 64) + (c ^ sU)] : 0.f;
      float dnU = hasDn ? su[(p0 + 64) + (c ^ sD)] : 0.f;
      float dnV = hasDn ? sv[(p0 + 64) + (c ^ sD)] : 0.f;
      float lfU = (c > 0) ? cu[c - 1] : luu;
      float lfV = (c > 0) ? cv[c - 1] : luv;
      float rtU = (c < 7) ? cu[c + 1] : ruu;
      float rtV = (c < 7) ? cv[c + 1] : ruv;
      nu[c] = ga[c] * (r0[c]*cu[c] + r1[c]*upU + r2[c]*dnU + r3[c]*lfU + r4[c]*rtU) + gb[c]*xu[c];
      nv[c] = ga[c] * (r0[c]*cv[c] + r1[c]*upV + r2[c]*dnV + r3[c]*lfV + r4[c]*rtV) + gb[c]*xv[c];
    }
    __syncthreads();
#pragma unroll
    for (int c = 0; c < 8; ++c) { su[p0 + (c ^ s)] = nu[c]; sv[p0 + (c ^ s)] = nv[c]; }
    __syncthreads();
  }
  bf16x8 ou, ov;
#pragma unroll
  for (int c = 0; c < 8; ++c) { ou[c] = f2bf(su[p0 + (c ^ s)]); ov[c] = f2bf(sv[p0 + (c ^ s)]); }
  *(bf16x8*)(Ug + pbase + p0) = ou;
  *(bf16x8*)(Vg + pbase + p0) = ov;
}

// ---------------- final GEMM: [u|v] @ W_out + x*D_skip ----------------
__global__ __launch_bounds__(256) void gemm_final(
    const short* __restrict__ U, const short* __restrict__ V,
    const short* __restrict__ Wt, const float* __restrict__ X,
    const float* __restrict__ Dskip, float* __restrict__ out)
{
  __shared__ short As[64 * 128];   // [k][m], 16B-chunk swizzled
  __shared__ short Bs[128 * 72];   // [c][k]
  const int tid = threadIdx.x;
  const int lane = tid & 63;
  const int wv = tid >> 6, wr = wv >> 1, wc = wv & 1;
  const int m0 = blockIdx.x * 128, c0 = blockIdx.y * 128;
  const int b = m0 >> 12, n0 = m0 & 4095;
  const int l15 = lane & 15, l4 = lane >> 4;
  f32x4 acc[4][4] = {};
  for (int k0 = 0; k0 < 768; k0 += 64) {
    const short* src = (k0 < 384) ? U : V;
    const int kp = (k0 >= 384) ? (k0 - 384) : k0;   // FIX: 384 is not a pow2 mask
    __syncthreads();
#pragma unroll
    for (int i = 0; i < 4; ++i) {
      int h = tid + i * 256;
      int k = h >> 4, cc = h & 15;
      bf16x8 tv = *(const bf16x8*)(src + (b * 384 + kp + k) * 4096 + n0 + cc * 8);
      int ccs = cc ^ (((k >> 3) & 3) << 1);
      *(bf16x8*)(As + k * 128 + ccs * 8) = tv;
    }
#pragma unroll
    for (int i = 0; i < 4; ++i) {
      int h = tid + i * 256;
      int c = h >> 3, kc = (h & 7) * 8;
      bf16x8 wvv = *(const bf16x8*)(Wt + (c0 + c) * 768 + k0 + kc);
      *(bf16x8*)(Bs + c * 72 + kc) = wvv;
    }
    __syncthreads();
#pragma unroll
    for (int kk = 0; kk < 2; ++kk) {
      bf16x8 af[4], bfv[4];
#pragma unroll
      for (int f = 0; f < 4; ++f) {
        const int mm = wr * 64 + f * 16 + l15;
        const int chunk = mm >> 3, wi = mm & 7;
        bf16x8 av;
#pragma unroll
        for (int jj = 0; jj < 8; ++jj) {
          int k = kk * 32 + l4 * 8 + jj;
          int ccs = chunk ^ (((k >> 3) & 3) << 1);
          av[jj] = As[k * 128 + ccs * 8 + wi];
        }
        af[f] = av;
        bfv[f] = *(const bf16x8*)(Bs + (wc * 64 + f * 16 + l15) * 72 + kk * 32 + l4 * 8);
      }
#pragma unroll
      for (int i = 0; i < 4; ++i)
#pragma unroll
        for (int j = 0; j < 4; ++j)
          acc[i][j] = __builtin_amdgcn_mfma_f32_16x16x32_bf16(af[i], bfv[j], acc[i][j], 0, 0, 0);
    }
  }
#pragma unroll
  for (int i = 0; i < 4; ++i)
#pragma unroll
    for (int j = 0; j < 4; ++j) {
      const int c = c0 + wc * 64 + j * 16 + l15;
      const int mb = m0 + wr * 64 + i * 16 + l4 * 4;
      const float ds = Dskip[c];
#pragma unroll
      for (int r = 0; r < 4; ++r) {
        int idx = (mb + r) * 384 + c;
        out[idx] = acc[i][j][r] + X[idx] * ds;
      }
    }
}

extern "C" void kernel_launch(void* const* d_in, const int* in_sizes, int n_in,
                              void* d_out, int out_size, void* d_ws, size_t ws_size,
                              hipStream_t stream) {
  (void)in_sizes; (void)n_in; (void)out_size; (void)ws_size;
  const float* x       = (const float*)d_in[0];
  const float* w_s1    = (const float*)d_in[1];
  const float* b_s1    = (const float*)d_in[2];
  const float* w_s2    = (const float*)d_in[3];
  const float* b_s2    = (const float*)d_in[4];
  const float* sb      = (const float*)d_in[5];
  const float* w_ga    = (const float*)d_in[6];
  const float* b_ga    = (const float*)d_in[7];
  const float* w_gb    = (const float*)d_in[8];
  const float* b_gb    = (const float*)d_in[9];
  const float* w_inj   = (const float*)d_in[10];
  const float* w_state = (const float*)d_in[11];
  const float* w_out   = (const float*)d_in[12];
  const float* dskip   = (const float*)d_in[13];
  const int*   ksp     = (const int*)d_in[14];
  float* out = (float*)d_out;

  char* ws = (char*)d_ws;
  size_t off = 0;
  auto alloc = [&](size_t bytes) -> void* {
    void* p = ws + off;
    off += (bytes + 255) & ~(size_t)255;
    return p;
  };
  short* t_state = (short*)alloc(768 * 384 * 2);
  short* t_inj   = (short*)alloc(768 * 384 * 2);
  short* t_ga    = (short*)alloc(384 * 384 * 2);
  short* t_gb    = (short*)alloc(384 * 384 * 2);
  short* t_s1    = (short*)alloc(384 * 384 * 2);
  short* t_out   = (short*)alloc(384 * 768 * 2);
  const size_t PL = (size_t)8 * 384 * 4096;
  short* ug  = (short*)alloc(PL * 2);
  short* vg  = (short*)alloc(PL * 2);
  short* xug = (short*)alloc(PL * 2);
  short* xvg = (short*)alloc(PL * 2);
  short* gag = (short*)alloc(PL * 2);
  short* gbg = (short*)alloc(PL * 2);
  short* s1  = (short*)alloc(PL * 2);
  float* psi = (float*)alloc((size_t)8 * 4 * 4096 * 4);
  float* R   = (float*)alloc((size_t)5 * 8 * 4 * 4096 * 4);

  prep_weights<<<dim3(5184), dim3(256), 0, stream>>>(
      w_state, w_inj, w_ga, w_gb, w_s1, w_out,
      t_state, t_inj, t_ga, t_gb, t_s1, t_out);
  gemm_x<0><<<dim3(256, 6), dim3(256), 0, stream>>>(x, t_state, nullptr, ug, vg);
  gemm_x<0><<<dim3(256, 6), dim3(256), 0, stream>>>(x, t_inj, nullptr, xug, xvg);
  gemm_x<1><<<dim3(256, 3), dim3(256), 0, stream>>>(x, t_ga, b_ga, gag, nullptr);
  gemm_x<1><<<dim3(256, 3), dim3(256), 0, stream>>>(x, t_gb, b_gb, gbg, nullptr);
  gemm_x<2><<<dim3(256, 3), dim3(256), 0, stream>>>(x, t_s1, b_s1, s1, nullptr);
  psi_kernel<<<dim3(8192), dim3(256), 0, stream>>>(s1, w_s2, b_s2, psi);
  routing_kernel<<<dim3(512), dim3(256), 0, stream>>>(psi, sb, R);
  transport_kernel<<<dim3(3072), dim3(512), 0, stream>>>(ug, vg, gag, gbg, xug, xvg, R, ksp);
  gemm_final<<<dim3(256, 3), dim3(256), 0, stream>>>(ug, vg, t_out, x, dskip, out);
}